// Round 1
// baseline (451.028 us; speedup 1.0000x reference)
//
#include <hip/hip_runtime.h>
#include <hip/hip_bf16.h>
#include <cmath>

// Problem constants
#define B_SZ 4096
#define D_SZ 16384
#define NKC 18          // (K+1)*C = 9*2
#define W2_STRIDE 32    // padded weight row stride (dwords), 128B aligned
#define RB 64           // rows per block (one per lane)
#define TD 128          // d-tile per block iteration

// ---------------------------------------------------------------------------
// Kernel 1: rearrange sms [9][16384][2] -> w2 [16384][32] (18 used per row)
// ---------------------------------------------------------------------------
__global__ void rearrange_w(const float* __restrict__ sms, float* __restrict__ w2) {
    int idx = blockIdx.x * 256 + threadIdx.x;
    if (idx >= D_SZ * NKC) return;
    int d = idx / NKC, j = idx % NKC;
    int k = j >> 1, c = j & 1;
    w2[(size_t)d * W2_STRIDE + j] = sms[(size_t)k * D_SZ * 2 + (size_t)d * 2 + c];
}

// ---------------------------------------------------------------------------
// Kernel 2: main projection. Each block: 64 rows x one D-segment.
// lane = row; weights broadcast via wave-uniform (scalar) loads.
// ---------------------------------------------------------------------------
__global__ __launch_bounds__(256, 4) void proj_main(
    const float* __restrict__ x, const float* __restrict__ w2,
    float* __restrict__ part, int nrowgrp, int dseg) {
    __shared__ float tile[RB * TD];   // 32 KiB, XOR-swizzled

    int rb  = (blockIdx.x % nrowgrp) * RB;
    int seg = blockIdx.x / nrowgrp;
    int d0  = seg * dseg;
    int tid  = threadIdx.x;
    int lane = tid & 63;
    int wave = __builtin_amdgcn_readfirstlane(tid >> 6);

    float acc[NKC];
#pragma unroll
    for (int j = 0; j < NKC; j++) acc[j] = 0.f;

    const int rswz = (lane & 7) << 2;   // read-side swizzle for this lane(=row)

    for (int t = 0; t < dseg; t += TD) {
        __syncthreads();   // protect tile from previous iteration's readers
        // ---- stage 64x128 tile, coalesced float4, swizzled LDS write ----
#pragma unroll
        for (int i = 0; i < 8; i++) {
            int flat = i * 1024 + tid * 4;          // dword index in tile
            int row  = flat >> 7;                   // /128
            int dd   = flat & 127;
            float4 v = *reinterpret_cast<const float4*>(
                &x[(size_t)(rb + row) * D_SZ + d0 + t + dd]);
            int wswz = (row & 7) << 2;
            *reinterpret_cast<float4*>(&tile[row * TD + (dd ^ wswz)]) = v;
        }
        __syncthreads();
        // ---- compute: wave w covers dd in [wave*32, wave*32+32) ----
        int base = wave * 32;
        for (int u = 0; u < 8; u++) {
            int dd = base + u * 4;
            float4 xv = *reinterpret_cast<const float4*>(
                &tile[lane * TD + (dd ^ rswz)]);
            const float* w = &w2[(size_t)(d0 + t + dd) * W2_STRIDE];
            float xq[4] = {xv.x, xv.y, xv.z, xv.w};
#pragma unroll
            for (int q = 0; q < 4; q++) {
#pragma unroll
                for (int j = 0; j < NKC; j++)
                    acc[j] = fmaf(xq[q], w[q * W2_STRIDE + j], acc[j]);
            }
        }
    }

    // ---- cross-wave reduction via LDS (reuse tile) ----
    __syncthreads();
#pragma unroll
    for (int j = 0; j < NKC; j++)
        tile[(wave * 64 + lane) * NKC + j] = acc[j];
    __syncthreads();
    if (wave == 0) {
#pragma unroll
        for (int j = 0; j < NKC; j++) {
            float s = tile[lane * NKC + j] + tile[(64 + lane) * NKC + j]
                    + tile[(128 + lane) * NKC + j] + tile[(192 + lane) * NKC + j];
            part[((size_t)seg * B_SZ + rb + lane) * NKC + j] = s;
        }
    }
}

// ---------------------------------------------------------------------------
// Kernel 3: orthogonality dots. One block per (c,k,j); writes (dot-eye)^2.
// ---------------------------------------------------------------------------
__global__ void orth_kernel(const float* __restrict__ sms, float* __restrict__ orth) {
    int b = blockIdx.x;               // 0..161
    int c = b / 81;
    int k = (b / 9) % 9;
    int j = b % 9;
    const float* pk = sms + (size_t)k * D_SZ * 2 + c;
    const float* pj = sms + (size_t)j * D_SZ * 2 + c;
    float s = 0.f;
    for (int d = threadIdx.x; d < D_SZ; d += 256)
        s += pk[(size_t)d * 2] * pj[(size_t)d * 2];
    // wave reduce (64 lanes)
    for (int off = 32; off; off >>= 1) s += __shfl_down(s, off, 64);
    __shared__ float sd[4];
    int lane = threadIdx.x & 63, wave = threadIdx.x >> 6;
    if (lane == 0) sd[wave] = s;
    __syncthreads();
    if (threadIdx.x == 0) {
        float dot = sd[0] + sd[1] + sd[2] + sd[3];
        float v = dot - (k == j ? 1.0f : 0.0f);
        orth[b] = v * v;
    }
}

// ---------------------------------------------------------------------------
// Kernel 4: epilogue. Sum segment partials, tanh weights, biases, outputs.
// ---------------------------------------------------------------------------
__global__ void epilogue(const float* __restrict__ part,
                         const float* __restrict__ sm_biases,
                         const float* __restrict__ embs,
                         const int* __restrict__ domains,
                         const float* __restrict__ cs_wt,
                         const float* __restrict__ orth,
                         float* __restrict__ out, int segs) {
    int row = blockIdx.x * 256 + threadIdx.x;
    if (row < B_SZ) {
        float proj[NKC];
#pragma unroll
        for (int j = 0; j < NKC; j++) proj[j] = 0.f;
        for (int s = 0; s < segs; s++) {
#pragma unroll
            for (int j = 0; j < NKC; j++)
                proj[j] += part[((size_t)s * B_SZ + row) * NKC + j];
        }
        int dom = domains[row];
        float cw[9];
        cw[0] = tanhf(cs_wt[0]);
#pragma unroll
        for (int k = 1; k < 9; k++) cw[k] = tanhf(embs[dom * 8 + (k - 1)]);
        float s0 = 0.f, s1 = 0.f;
#pragma unroll
        for (int k = 0; k < 9; k++) {
            s0 += cw[k] * (proj[2 * k]     + sm_biases[2 * k]);
            s1 += cw[k] * (proj[2 * k + 1] + sm_biases[2 * k + 1]);
        }
        out[(size_t)row * 2 + 0] = s0;
        out[(size_t)row * 2 + 1] = s1;
        out[2 * B_SZ + (size_t)row * 2 + 0] = proj[0] + sm_biases[0];
        out[2 * B_SZ + (size_t)row * 2 + 1] = proj[1] + sm_biases[1];
    }
    if (blockIdx.x == 0 && threadIdx.x == 0) {
        float l = 0.f;
        for (int e = 0; e < 162; e++) l += orth[e];
        out[4 * B_SZ] = l / 162.f;
    }
}

// ---------------------------------------------------------------------------
extern "C" void kernel_launch(void* const* d_in, const int* in_sizes, int n_in,
                              void* d_out, int out_size, void* d_ws, size_t ws_size,
                              hipStream_t stream) {
    const float* x         = (const float*)d_in[0];
    const int*   domains   = (const int*)d_in[1];
    const float* sms       = (const float*)d_in[2];
    const float* sm_biases = (const float*)d_in[3];
    const float* embs      = (const float*)d_in[4];
    const float* cs_wt     = (const float*)d_in[5];
    float* out = (float*)d_out;

    // ws layout: [ w2: 16384*32 f32 | part: segs*4096*18 f32 | orth: 162 f32 ]
    float* w2 = (float*)d_ws;
    size_t w2_elems = (size_t)D_SZ * W2_STRIDE;
    int segs = 16;
    while (segs > 1 &&
           (w2_elems + (size_t)segs * B_SZ * NKC + 162) * 4 > ws_size)
        segs >>= 1;
    float* part = w2 + w2_elems;
    float* orth = part + (size_t)segs * B_SZ * NKC;
    int dseg = D_SZ / segs;
    int nrowgrp = B_SZ / RB;   // 64

    rearrange_w<<<(D_SZ * NKC + 255) / 256, 256, 0, stream>>>(sms, w2);
    proj_main<<<nrowgrp * segs, 256, 0, stream>>>(x, w2, part, nrowgrp, dseg);
    orth_kernel<<<162, 256, 0, stream>>>(sms, orth);
    epilogue<<<(B_SZ + 255) / 256, 256, 0, stream>>>(
        part, sm_biases, embs, domains, cs_wt, orth, out, segs);
}

// Round 3
// 403.201 us; speedup vs baseline: 1.1186x; 1.1186x over previous
//
#include <hip/hip_runtime.h>
#include <hip/hip_bf16.h>
#include <cmath>

#define B_SZ 4096
#define D_SZ 16384
#define NKC 18   // (K+1)*C

// ---------------------------------------------------------------------------
// Main projection: grid = 16 dblocks x 64 rowgroups. Block = 256 thr = 4 waves.
// Wave owns a fixed 256-d slice; lane owns 4 d's -> 72 weights in VGPRs.
// Per row: float4 x load, 72 FMA, 21-shfl split-j butterfly reduce,
// LDS stage, flush to ws partials every 16 rows. ATOMIC=true variant adds
// directly to accbuf (fallback if ws is small).
// ---------------------------------------------------------------------------
template <bool ATOMIC>
__global__ void proj_stream(const float* __restrict__ x,
                            const float* __restrict__ sms,
                            float* __restrict__ part) {
    const int bid  = blockIdx.x;
    const int dblk = bid & 15;
    const int r0   = (bid >> 4) * 64;
    const int tid  = threadIdx.x;
    const int lane = tid & 63;
    const int wave = tid >> 6;
    const int dbase = dblk * 1024 + wave * 256 + lane * 4;

    // ---- preload 4d x 18j weights into registers (once) ----
    float wr[72];
#pragma unroll
    for (int k = 0; k < 9; ++k)
#pragma unroll
        for (int q = 0; q < 4; ++q) {
            const float2 wv = *reinterpret_cast<const float2*>(
                sms + (size_t)k * (D_SZ * 2) + (size_t)(dbase + q) * 2);
            wr[q * 18 + k * 2 + 0] = wv.x;
            wr[q * 18 + k * 2 + 1] = wv.y;
        }

    // ---- lane ownership (k,c) for the butterfly output ----
    int start = 0, len = 9;
    if (lane & 2)  { start += 5; len -= 5; } else { len = len < 5 ? len : 5; }
    if (lane & 4)  { start += 3; len -= 3; } else { len = len < 3 ? len : 3; }
    if (lane & 8)  { start += 2; len -= 2; } else { len = len < 2 ? len : 2; }
    if (lane & 16) { start += 1; len -= 1; } else { len = len < 1 ? len : 1; }
    const bool valid = (len >= 1) && (lane < 32) && (start <= 8);
    const int  kj    = start * 2 + (lane & 1);

    __shared__ float stage[4][16][NKC];
    const float* xrow = x + (size_t)r0 * D_SZ + dbase;

    for (int bt = 0; bt < 4; ++bt) {
#pragma unroll 2
        for (int rl = 0; rl < 16; ++rl) {
            const int rr = bt * 16 + rl;
            const float4 xv =
                *reinterpret_cast<const float4*>(xrow + (size_t)rr * D_SZ);
            // ---- 72 FMA ----
            float acc[18];
#pragma unroll
            for (int j = 0; j < 18; ++j) acc[j] = xv.x * wr[j];
#pragma unroll
            for (int j = 0; j < 18; ++j) acc[j] = fmaf(xv.y, wr[18 + j], acc[j]);
#pragma unroll
            for (int j = 0; j < 18; ++j) acc[j] = fmaf(xv.z, wr[36 + j], acc[j]);
#pragma unroll
            for (int j = 0; j < 18; ++j) acc[j] = fmaf(xv.w, wr[54 + j], acc[j]);

            // ---- split-j butterfly reduction over 64 lanes (21 shfl) ----
            float v[10];
#pragma unroll
            for (int i = 0; i < 9; ++i) {
                float send = (lane & 1) ? acc[2 * i] : acc[2 * i + 1];
                float r = __shfl_xor(send, 1, 64);
                v[i] = ((lane & 1) ? acc[2 * i + 1] : acc[2 * i]) + r;
            }
            v[9] = 0.f;
            float v2[6];
#pragma unroll
            for (int i = 0; i < 5; ++i) {
                float send = (lane & 2) ? v[i] : v[5 + i];
                float r = __shfl_xor(send, 2, 64);
                v2[i] = ((lane & 2) ? v[5 + i] : v[i]) + r;
            }
            v2[5] = 0.f;
            float v3[4];
#pragma unroll
            for (int i = 0; i < 3; ++i) {
                float send = (lane & 4) ? v2[i] : v2[3 + i];
                float r = __shfl_xor(send, 4, 64);
                v3[i] = ((lane & 4) ? v2[3 + i] : v2[i]) + r;
            }
            v3[3] = 0.f;
            float v4[2];
#pragma unroll
            for (int i = 0; i < 2; ++i) {
                float send = (lane & 8) ? v3[i] : v3[2 + i];
                float r = __shfl_xor(send, 8, 64);
                v4[i] = ((lane & 8) ? v3[2 + i] : v3[i]) + r;
            }
            float send5 = (lane & 16) ? v4[0] : v4[1];
            float r5 = __shfl_xor(send5, 16, 64);
            float s = ((lane & 16) ? v4[1] : v4[0]) + r5;
            s += __shfl_xor(s, 32, 64);

            if (ATOMIC) {
                if (valid)
                    atomicAdd(&part[(size_t)(r0 + rr) * NKC + kj], s);
            } else {
                if (valid) stage[wave][rl][kj] = s;
            }
        }
        if (!ATOMIC) {
            __syncthreads();
            for (int idx = tid; idx < 16 * NKC; idx += 256) {
                const int rl = idx / NKC, jj = idx % NKC;
                const float sum = stage[0][rl][jj] + stage[1][rl][jj] +
                                  stage[2][rl][jj] + stage[3][rl][jj];
                part[((size_t)dblk * B_SZ + (r0 + bt * 16 + rl)) * NKC + jj] = sum;
            }
            __syncthreads();
        }
    }
}

// ---------------------------------------------------------------------------
// Orthogonality partial dots: 45 (k<=j) pairs x 4 d-segments, both c at once.
// Coalesced float2 loads; block reduce; atomicAdd into dots[90].
// ---------------------------------------------------------------------------
__global__ void orth_partial(const float* __restrict__ sms,
                             float* __restrict__ dots) {
    const int p = blockIdx.x >> 2;
    const int dseg = blockIdx.x & 3;
    int k = 0, rem = p;
    while (rem >= 9 - k) { rem -= 9 - k; ++k; }
    const int j = k + rem;
    const int tid = threadIdx.x;
    const float* rk = sms + (size_t)k * (D_SZ * 2);
    const float* rj = sms + (size_t)j * (D_SZ * 2);
    float d0 = 0.f, d1 = 0.f;
    const int dbase = dseg * 4096;
#pragma unroll 4
    for (int i = 0; i < 16; ++i) {
        const int d = dbase + i * 256 + tid;
        const float2 a = *reinterpret_cast<const float2*>(rk + (size_t)d * 2);
        const float2 b = *reinterpret_cast<const float2*>(rj + (size_t)d * 2);
        d0 = fmaf(a.x, b.x, d0);
        d1 = fmaf(a.y, b.y, d1);
    }
    for (int m = 32; m; m >>= 1) {
        d0 += __shfl_xor(d0, m, 64);
        d1 += __shfl_xor(d1, m, 64);
    }
    __shared__ float sd[8];
    const int lane = tid & 63, wv = tid >> 6;
    if (lane == 0) { sd[wv * 2] = d0; sd[wv * 2 + 1] = d1; }
    __syncthreads();
    if (tid == 0) {
        atomicAdd(&dots[p * 2 + 0], sd[0] + sd[2] + sd[4] + sd[6]);
        atomicAdd(&dots[p * 2 + 1], sd[1] + sd[3] + sd[5] + sd[7]);
    }
}

// ---------------------------------------------------------------------------
// Epilogue: sum slice partials, tanh-weight combine, biases, orth finalize.
// SLICES=16 (staged path) or 1 (atomic path).
// ---------------------------------------------------------------------------
template <int SLICES>
__global__ void epilogue2(const float* __restrict__ part,
                          const float* __restrict__ sm_biases,
                          const float* __restrict__ embs,
                          const int* __restrict__ domains,
                          const float* __restrict__ cs_wt,
                          const float* __restrict__ dots,
                          float* __restrict__ out) {
    if (blockIdx.x == 16) {  // orth finalize on wave 0
        const int lane = threadIdx.x;
        if (lane >= 64) return;
        float prt = 0.f;
        if (lane < 45) {
            int k = 0, rem = lane;
            while (rem >= 9 - k) { rem -= 9 - k; ++k; }
            const int j = k + rem;
            const float e = (k == j) ? 1.f : 0.f;
            const float m = (k == j) ? 1.f : 2.f;
            const float a = dots[lane * 2] - e;
            const float b = dots[lane * 2 + 1] - e;
            prt = m * (a * a + b * b);
        }
        for (int mm = 32; mm; mm >>= 1) prt += __shfl_xor(prt, mm, 64);
        if (lane == 0) out[4 * B_SZ] = prt / 162.f;
        return;
    }
    const int row = blockIdx.x * 256 + threadIdx.x;
    float proj[18];
#pragma unroll
    for (int jj = 0; jj < 18; ++jj) proj[jj] = 0.f;
    for (int sl = 0; sl < SLICES; ++sl)
#pragma unroll
        for (int jj = 0; jj < 18; ++jj)
            proj[jj] += part[((size_t)sl * B_SZ + row) * NKC + jj];
    const int dom = domains[row];
    float cw[9];
    cw[0] = tanhf(cs_wt[0]);
#pragma unroll
    for (int k = 1; k < 9; ++k) cw[k] = tanhf(embs[dom * 8 + k - 1]);
    float s0 = 0.f, s1 = 0.f;
#pragma unroll
    for (int k = 0; k < 9; ++k) {
        s0 += cw[k] * (proj[2 * k]     + sm_biases[2 * k]);
        s1 += cw[k] * (proj[2 * k + 1] + sm_biases[2 * k + 1]);
    }
    out[(size_t)row * 2 + 0] = s0;
    out[(size_t)row * 2 + 1] = s1;
    out[2 * B_SZ + (size_t)row * 2 + 0] = proj[0] + sm_biases[0];
    out[2 * B_SZ + (size_t)row * 2 + 1] = proj[1] + sm_biases[1];
}

// ---------------------------------------------------------------------------
extern "C" void kernel_launch(void* const* d_in, const int* in_sizes, int n_in,
                              void* d_out, int out_size, void* d_ws, size_t ws_size,
                              hipStream_t stream) {
    const float* x         = (const float*)d_in[0];
    const int*   domains   = (const int*)d_in[1];
    const float* sms       = (const float*)d_in[2];
    const float* sm_biases = (const float*)d_in[3];
    const float* embs      = (const float*)d_in[4];
    const float* cs_wt     = (const float*)d_in[5];
    float* out = (float*)d_out;

    const size_t staged_elems = (size_t)16 * B_SZ * NKC;   // 4.72 MB
    const bool   staged = ws_size >= (staged_elems + 90) * sizeof(float);

    if (staged) {
        float* part = (float*)d_ws;
        float* dots = part + staged_elems;
        hipMemsetAsync(dots, 0, 90 * sizeof(float), stream);
        proj_stream<false><<<1024, 256, 0, stream>>>(x, sms, part);
        orth_partial<<<180, 256, 0, stream>>>(sms, dots);
        epilogue2<16><<<17, 256, 0, stream>>>(part, sm_biases, embs, domains,
                                              cs_wt, dots, out);
    } else {
        float* accb = (float*)d_ws;                        // 295 KB
        float* dots = accb + (size_t)B_SZ * NKC;
        hipMemsetAsync(accb, 0, ((size_t)B_SZ * NKC + 90) * sizeof(float), stream);
        proj_stream<true><<<1024, 256, 0, stream>>>(x, sms, accb);
        orth_partial<<<180, 256, 0, stream>>>(sms, dots);
        epilogue2<1><<<17, 256, 0, stream>>>(accb, sm_biases, embs, domains,
                                             cs_wt, dots, out);
    }
}